// Round 1
// baseline (29969.479 us; speedup 1.0000x reference)
//
#include <hip/hip_runtime.h>
#include <math.h>

// DynamiSE: GCN + 2x RK4 neural ODE + combine/LN.
// N=100000 nodes, IN=128, HID=32, 10 RK4 steps, h=0.1.

#define TPB 256

// ---------- small utility kernels ----------

__global__ void set_ones_f32(float* __restrict__ p, int n) {
    int i = blockIdx.x * blockDim.x + threadIdx.x;
    if (i < n) p[i] = 1.0f;
}

__global__ void deg_accum(const int* __restrict__ dst, int e, float* __restrict__ deg) {
    int i = blockIdx.x * blockDim.x + threadIdx.x;
    if (i < e) atomicAdd(&deg[dst[i]], 1.0f);
}

__global__ void rsqrt_inplace(float* __restrict__ p, int n) {
    int i = blockIdx.x * blockDim.x + threadIdx.x;
    if (i < n) p[i] = rsqrtf(p[i]);
}

__global__ void coef_kernel(float* __restrict__ coef, const int* __restrict__ src,
                            const int* __restrict__ dst, const float* __restrict__ dinv, int e) {
    int i = blockIdx.x * blockDim.x + threadIdx.x;
    if (i < e) coef[i] = dinv[src[i]] * dinv[dst[i]];
}

// ---------- matmuls ----------
// x[N,32] @ W[32,32] -> hlin; kbuf = hlin * dinv^2 (self-loop init, full overwrite)
__global__ void mm32_kernel(const float* __restrict__ x, const float* __restrict__ W,
                            const float* __restrict__ dinv, float* __restrict__ hlin,
                            float* __restrict__ kbuf, int N) {
    __shared__ float Ws[32][32];
    __shared__ float xs[8][32];
    int tid = threadIdx.x;
    for (int i = tid; i < 32 * 32; i += TPB) Ws[i >> 5][i & 31] = W[i];
    int base = blockIdx.x * 8;
    {
        int idx = base * 32 + tid;
        xs[tid >> 5][tid & 31] = (idx < N * 32) ? x[idx] : 0.0f;
    }
    __syncthreads();
    int row = tid >> 5, c = tid & 31;
    int gr = base + row;
    float acc = 0.0f;
#pragma unroll
    for (int k = 0; k < 32; ++k) acc += xs[row][k] * Ws[k][c];
    if (gr < N) {
        float dv = dinv[gr];
        hlin[gr * 32 + c] = acc;
        kbuf[gr * 32 + c] = acc * dv * dv;
    }
}

// H_t[N,128] @ W[128,32] -> hlin; kbuf = hlin * dinv^2
__global__ void mm128_kernel(const float* __restrict__ x, const float* __restrict__ W,
                             const float* __restrict__ dinv, float* __restrict__ hlin,
                             float* __restrict__ kbuf, int N) {
    __shared__ float Ws[128][32]; // 16 KB
    __shared__ float xs[8][128];  // 4 KB
    int tid = threadIdx.x;
    for (int i = tid; i < 128 * 32; i += TPB) Ws[i >> 5][i & 31] = W[i];
    int base = blockIdx.x * 8;
    for (int i = tid; i < 8 * 128; i += TPB) {
        int idx = base * 128 + i;
        xs[i >> 7][i & 127] = (idx < N * 128) ? x[idx] : 0.0f;
    }
    __syncthreads();
    int row = tid >> 5, c = tid & 31;
    int gr = base + row;
    float acc = 0.0f;
#pragma unroll
    for (int k = 0; k < 128; ++k) acc += xs[row][k] * Ws[k][c];
    if (gr < N) {
        float dv = dinv[gr];
        hlin[gr * 32 + c] = acc;
        kbuf[gr * 32 + c] = acc * dv * dv;
    }
}

// ---------- edge scatter: kbuf[dst] += hlin[src] * coef ----------
// 8 threads per edge, float4 gather + 4 scalar fp32 atomics each.
__global__ void scatter_kernel(const int* __restrict__ src, const int* __restrict__ dst,
                               const float* __restrict__ coef, const float* __restrict__ dinv,
                               const float* __restrict__ hlin, float* __restrict__ kbuf, int E) {
    int tid = blockIdx.x * blockDim.x + threadIdx.x;
    int e = tid >> 3, q = tid & 7;
    if (e >= E) return;
    int s = src[e], d = dst[e];
    float cf = coef ? coef[e] : dinv[s] * dinv[d];
    float4 v = *(const float4*)(hlin + s * 32 + q * 4);
    float* kp = kbuf + d * 32 + q * 4;
    atomicAdd(kp + 0, v.x * cf);
    atomicAdd(kp + 1, v.y * cf);
    atomicAdd(kp + 2, v.z * cf);
    atomicAdd(kp + 3, v.w * cf);
}

// ---------- RK4 stage finisher ----------
// kv = relu(kbuf + b) [* sigmoid(t*wt) if wt]
// stage 0: x = kv; x2 = kv                       (init-GCN output -> both ODE states)
// stage 1: ksum = kv;      xt = x + 0.05*kv
// stage 2: ksum += 2*kv;   xt = x + 0.05*kv
// stage 3: ksum += 2*kv;   xt = x + 0.1*kv
// stage 4: x += (0.1/6)*(ksum + kv)
__global__ void finish_kernel(const float* __restrict__ kbuf, const float* __restrict__ bias,
                              const float* __restrict__ wt, float t, float* __restrict__ ksum,
                              float* __restrict__ x, float* __restrict__ xt,
                              float* __restrict__ x2, int stage, int nv4) {
    int i = blockIdx.x * blockDim.x + threadIdx.x;
    if (i >= nv4) return;
    int c0 = (i * 4) & 31;
    float4 kv = ((const float4*)kbuf)[i];
    float4 bb = *(const float4*)(bias + c0);
    kv.x = fmaxf(kv.x + bb.x, 0.0f);
    kv.y = fmaxf(kv.y + bb.y, 0.0f);
    kv.z = fmaxf(kv.z + bb.z, 0.0f);
    kv.w = fmaxf(kv.w + bb.w, 0.0f);
    if (wt) {
        float4 w = *(const float4*)(wt + c0);
        kv.x *= 1.0f / (1.0f + expf(-t * w.x));
        kv.y *= 1.0f / (1.0f + expf(-t * w.y));
        kv.z *= 1.0f / (1.0f + expf(-t * w.z));
        kv.w *= 1.0f / (1.0f + expf(-t * w.w));
    }
    if (stage == 0) {
        ((float4*)x)[i] = kv;
        ((float4*)x2)[i] = kv;
        return;
    }
    if (stage == 4) {
        float4 ks = ((const float4*)ksum)[i];
        float4 xv = ((float4*)x)[i];
        const float cc = 0.1f / 6.0f;
        xv.x += cc * (ks.x + kv.x);
        xv.y += cc * (ks.y + kv.y);
        xv.z += cc * (ks.z + kv.z);
        xv.w += cc * (ks.w + kv.w);
        ((float4*)x)[i] = xv;
        return;
    }
    float a = (stage == 3) ? 0.1f : 0.05f;
    float4 xv = ((const float4*)x)[i];
    float4 xo;
    xo.x = xv.x + a * kv.x;
    xo.y = xv.y + a * kv.y;
    xo.z = xv.z + a * kv.z;
    xo.w = xv.w + a * kv.w;
    ((float4*)xt)[i] = xo;
    if (stage == 1) {
        ((float4*)ksum)[i] = kv;
    } else {
        float4 ks = ((const float4*)ksum)[i];
        ks.x += 2.0f * kv.x;
        ks.y += 2.0f * kv.y;
        ks.z += 2.0f * kv.z;
        ks.w += 2.0f * kv.w;
        ((float4*)ksum)[i] = ks;
    }
}

// ---------- combine + layernorm ----------
// z = [zp|zn] @ Wc[64,32] + bc; LN over 32 channels; out = (z-mu)*rsqrt(var+eps)*g + b
__global__ void combine_kernel(const float* __restrict__ zp, const float* __restrict__ zn,
                               const float* __restrict__ Wc, const float* __restrict__ bc,
                               const float* __restrict__ g, const float* __restrict__ be,
                               float* __restrict__ out, int N) {
    __shared__ float Ws[64][32]; // 8 KB
    __shared__ float zs[8][64];  // 2 KB
    int tid = threadIdx.x;
    for (int i = tid; i < 64 * 32; i += TPB) Ws[i >> 5][i & 31] = Wc[i];
    int base = blockIdx.x * 8;
    {
        int r = tid >> 5, c = tid & 31;
        int gr = base + r;
        zs[r][c] = (gr < N) ? zp[gr * 32 + c] : 0.0f;
        zs[r][32 + c] = (gr < N) ? zn[gr * 32 + c] : 0.0f;
    }
    __syncthreads();
    int row = tid >> 5, c = tid & 31;
    int gr = base + row;
    float acc = bc[c];
#pragma unroll
    for (int k = 0; k < 64; ++k) acc += zs[row][k] * Ws[k][c];
    // layernorm across the 32 lanes of this row
    float s = acc, sq = acc * acc;
#pragma unroll
    for (int off = 16; off; off >>= 1) {
        s += __shfl_xor(s, off, 32);
        sq += __shfl_xor(sq, off, 32);
    }
    float mu = s * (1.0f / 32.0f);
    float var = sq * (1.0f / 32.0f) - mu * mu;
    float y = (acc - mu) * rsqrtf(var + 1e-5f) * g[c] + be[c];
    if (gr < N) out[gr * 32 + c] = y;
}

// ---------- host orchestration ----------

extern "C" void kernel_launch(void* const* d_in, const int* in_sizes, int n_in,
                              void* d_out, int out_size, void* d_ws, size_t ws_size,
                              hipStream_t stream) {
    const float* H_t = (const float*)d_in[0];
    const int* Apos = (const int*)d_in[1];
    const int* Aneg = (const int*)d_in[2];
    const int* dApos = (const int*)d_in[3];
    const int* dAneg = (const int*)d_in[4];
    const float* W_init = (const float*)d_in[5];
    const float* b_init = (const float*)d_in[6];
    const float* W_pos = (const float*)d_in[7];
    const float* b_pos = (const float*)d_in[8];
    const float* wt_pos = (const float*)d_in[9];
    const float* W_neg = (const float*)d_in[10];
    const float* b_neg = (const float*)d_in[11];
    const float* wt_neg = (const float*)d_in[12];
    const float* W_comb = (const float*)d_in[13];
    const float* b_comb = (const float*)d_in[14];
    const float* ln_g = (const float*)d_in[15];
    const float* ln_b = (const float*)d_in[16];

    const int N = in_sizes[0] / 128;
    const int E1 = in_sizes[1] / 2;   // A_pos edges
    const int E2 = in_sizes[2] / 2;   // A_neg edges
    const int DE1 = in_sizes[3] / 2;  // dA_pos edges
    const int DE2 = in_sizes[4] / 2;  // dA_neg edges

    const int* Apos_src = Apos, * Apos_dst = Apos + E1;
    const int* Aneg_src = Aneg, * Aneg_dst = Aneg + E2;
    const int* dApos_src = dApos, * dApos_dst = dApos + DE1;
    const int* dAneg_src = dAneg, * dAneg_dst = dAneg + DE2;

    const int n32 = N * 32;
    const int nv4 = n32 / 4;

    // workspace layout (floats)
    float* ws = (float*)d_ws;
    float* x_pos = ws;            // N*32
    float* x_neg = x_pos + n32;   // N*32
    float* hlin = x_neg + n32;    // N*32
    float* kbuf = hlin + n32;     // N*32
    float* ksum = kbuf + n32;     // N*32
    float* xt = ksum + n32;       // N*32
    float* dinv_all = xt + n32;   // N
    float* dinv_pos = dinv_all + N; // N
    float* dinv_neg = dinv_pos + N; // N
    float* coef_pos = dinv_neg + N; // DE1
    float* coef_neg = coef_pos + DE1; // DE2

    dim3 blk(TPB);
    auto gblk = [](int n) { return dim3((n + TPB - 1) / TPB); };
    dim3 grid_rows((N + 7) / 8);

    // degrees: deg = 1 + indeg, then dinv = rsqrt(deg)
    set_ones_f32<<<gblk(3 * N), blk, 0, stream>>>(dinv_all, 3 * N);
    deg_accum<<<gblk(E1), blk, 0, stream>>>(Apos_dst, E1, dinv_all);
    deg_accum<<<gblk(E2), blk, 0, stream>>>(Aneg_dst, E2, dinv_all);
    deg_accum<<<gblk(DE1), blk, 0, stream>>>(dApos_dst, DE1, dinv_pos);
    deg_accum<<<gblk(DE2), blk, 0, stream>>>(dAneg_dst, DE2, dinv_neg);
    rsqrt_inplace<<<gblk(3 * N), blk, 0, stream>>>(dinv_all, 3 * N);
    coef_kernel<<<gblk(DE1), blk, 0, stream>>>(coef_pos, dApos_src, dApos_dst, dinv_pos, DE1);
    coef_kernel<<<gblk(DE2), blk, 0, stream>>>(coef_neg, dAneg_src, dAneg_dst, dinv_neg, DE2);

    // init GCN: H0 = relu(gcn(H_t)) -> x_pos, x_neg
    mm128_kernel<<<grid_rows, blk, 0, stream>>>(H_t, W_init, dinv_all, hlin, kbuf, N);
    scatter_kernel<<<gblk(E1 * 8), blk, 0, stream>>>(Apos_src, Apos_dst, nullptr, dinv_all, hlin, kbuf, E1);
    scatter_kernel<<<gblk(E2 * 8), blk, 0, stream>>>(Aneg_src, Aneg_dst, nullptr, dinv_all, hlin, kbuf, E2);
    finish_kernel<<<gblk(nv4), blk, 0, stream>>>(kbuf, b_init, nullptr, 0.0f, nullptr,
                                                 x_pos, nullptr, x_neg, 0, nv4);

    // two ODEs
    for (int ode = 0; ode < 2; ++ode) {
        float* x = ode ? x_neg : x_pos;
        const float* W = ode ? W_neg : W_pos;
        const float* b = ode ? b_neg : b_pos;
        const float* wt = ode ? wt_neg : wt_pos;
        const float* dinv = ode ? dinv_neg : dinv_pos;
        const float* coef = ode ? coef_neg : coef_pos;
        const int* esrc = ode ? dAneg_src : dApos_src;
        const int* edst = ode ? dAneg_dst : dApos_dst;
        const int Eo = ode ? DE2 : DE1;
        dim3 sgrid = gblk(Eo * 8);

        for (int s = 0; s < 10; ++s) {
            float t0 = 0.1f * (float)s;
            // k1
            mm32_kernel<<<grid_rows, blk, 0, stream>>>(x, W, dinv, hlin, kbuf, N);
            scatter_kernel<<<sgrid, blk, 0, stream>>>(esrc, edst, coef, nullptr, hlin, kbuf, Eo);
            finish_kernel<<<gblk(nv4), blk, 0, stream>>>(kbuf, b, wt, t0, ksum, x, xt, nullptr, 1, nv4);
            // k2
            mm32_kernel<<<grid_rows, blk, 0, stream>>>(xt, W, dinv, hlin, kbuf, N);
            scatter_kernel<<<sgrid, blk, 0, stream>>>(esrc, edst, coef, nullptr, hlin, kbuf, Eo);
            finish_kernel<<<gblk(nv4), blk, 0, stream>>>(kbuf, b, wt, t0 + 0.05f, ksum, x, xt, nullptr, 2, nv4);
            // k3
            mm32_kernel<<<grid_rows, blk, 0, stream>>>(xt, W, dinv, hlin, kbuf, N);
            scatter_kernel<<<sgrid, blk, 0, stream>>>(esrc, edst, coef, nullptr, hlin, kbuf, Eo);
            finish_kernel<<<gblk(nv4), blk, 0, stream>>>(kbuf, b, wt, t0 + 0.05f, ksum, x, xt, nullptr, 3, nv4);
            // k4
            mm32_kernel<<<grid_rows, blk, 0, stream>>>(xt, W, dinv, hlin, kbuf, N);
            scatter_kernel<<<sgrid, blk, 0, stream>>>(esrc, edst, coef, nullptr, hlin, kbuf, Eo);
            finish_kernel<<<gblk(nv4), blk, 0, stream>>>(kbuf, b, wt, t0 + 0.1f, ksum, x, nullptr, nullptr, 4, nv4);
        }
    }

    // combine + layernorm
    combine_kernel<<<grid_rows, blk, 0, stream>>>(x_pos, x_neg, W_comb, b_comb, ln_g, ln_b,
                                                  (float*)d_out, N);
}

// Round 2
// 4492.993 us; speedup vs baseline: 6.6703x; 6.6703x over previous
//
#include <hip/hip_runtime.h>
#include <math.h>

// DynamiSE: GCN + 2x RK4 neural ODE + combine/LN.
// N=100000 nodes, IN=128, HID=32, 10 RK4 steps, h=0.1.
// R1: CSR-gather aggregation (no fp32 atomics in hot loop); coef folded into
//     matmul output scaling (hs = dinv * (x@W)); scatter+finish fused.

#define TPB 256
#define SCAN_T 1024

// ---------- CSR build ----------

__global__ void count_dst(const int* __restrict__ dst, int e, int* __restrict__ cnt) {
    int i = blockIdx.x * blockDim.x + threadIdx.x;
    if (i < e) atomicAdd(&cnt[dst[i]], 1);
}

__global__ void dinv_from_cnt(const int* __restrict__ cnt, float* __restrict__ dinv, int n) {
    int i = blockIdx.x * blockDim.x + threadIdx.x;
    if (i < n) dinv[i] = rsqrtf(1.0f + (float)cnt[i]);
}

// per-block exclusive scan over SCAN_T elements; emits block totals
__global__ void scan_block(const int* __restrict__ in, int n, int* __restrict__ out,
                           int* __restrict__ bsums) {
    __shared__ int sh[SCAN_T];
    int tx = threadIdx.x;
    int g = blockIdx.x * SCAN_T + tx;
    int v = (g < n) ? in[g] : 0;
    sh[tx] = v;
    __syncthreads();
    for (int off = 1; off < SCAN_T; off <<= 1) {
        int t = (tx >= off) ? sh[tx - off] : 0;
        __syncthreads();
        sh[tx] += t;
        __syncthreads();
    }
    if (g < n) out[g] = sh[tx] - v; // exclusive
    if (tx == SCAN_T - 1) bsums[blockIdx.x] = sh[tx];
}

// single-block exclusive scan of block sums (nb <= SCAN_T)
__global__ void scan_sums(int* __restrict__ bsums, int nb) {
    __shared__ int sh[SCAN_T];
    int tx = threadIdx.x;
    int v = (tx < nb) ? bsums[tx] : 0;
    sh[tx] = v;
    __syncthreads();
    for (int off = 1; off < SCAN_T; off <<= 1) {
        int t = (tx >= off) ? sh[tx - off] : 0;
        __syncthreads();
        sh[tx] += t;
        __syncthreads();
    }
    if (tx < nb) bsums[tx] = sh[tx] - v;
}

__global__ void scan_add(int* __restrict__ offs, const int* __restrict__ bsums, int n, int total) {
    int g = blockIdx.x * blockDim.x + threadIdx.x;
    if (g < n) offs[g] += bsums[g >> 10]; // must match SCAN_T=1024 partitioning
    if (g == 0) offs[n] = total;
}

__global__ void fill_csr(const int* __restrict__ src, const int* __restrict__ dst, int E,
                         const int* __restrict__ offs, int* __restrict__ cursor,
                         int* __restrict__ csr) {
    int e = blockIdx.x * blockDim.x + threadIdx.x;
    if (e >= E) return;
    int d = dst[e];
    int pos = offs[d] + atomicAdd(&cursor[d], 1);
    csr[pos] = src[e];
}

// ---------- matmuls: hs = dinv * (x @ W) ----------

__global__ void mm32_kernel(const float* __restrict__ x, const float* __restrict__ W,
                            const float* __restrict__ dinv, float* __restrict__ hs, int N) {
    __shared__ float Ws[32][32];
    __shared__ float xs[8][32];
    int tid = threadIdx.x;
    for (int i = tid; i < 32 * 32; i += TPB) Ws[i >> 5][i & 31] = W[i];
    int base = blockIdx.x * 8;
    {
        int idx = base * 32 + tid;
        xs[tid >> 5][tid & 31] = (idx < N * 32) ? x[idx] : 0.0f;
    }
    __syncthreads();
    int row = tid >> 5, c = tid & 31;
    int gr = base + row;
    float acc = 0.0f;
#pragma unroll
    for (int k = 0; k < 32; ++k) acc += xs[row][k] * Ws[k][c];
    if (gr < N) hs[gr * 32 + c] = acc * dinv[gr];
}

__global__ void mm128_kernel(const float* __restrict__ x, const float* __restrict__ W,
                             const float* __restrict__ dinv, float* __restrict__ hs, int N) {
    __shared__ float Ws[128][32]; // 16 KB
    __shared__ float xs[8][128];  // 4 KB
    int tid = threadIdx.x;
    for (int i = tid; i < 128 * 32; i += TPB) Ws[i >> 5][i & 31] = W[i];
    int base = blockIdx.x * 8;
    for (int i = tid; i < 8 * 128; i += TPB) {
        int idx = base * 128 + i;
        xs[i >> 7][i & 127] = (idx < N * 128) ? x[idx] : 0.0f;
    }
    __syncthreads();
    int row = tid >> 5, c = tid & 31;
    int gr = base + row;
    float acc = 0.0f;
#pragma unroll
    for (int k = 0; k < 128; ++k) acc += xs[row][k] * Ws[k][c];
    if (gr < N) hs[gr * 32 + c] = acc * dinv[gr];
}

// ---------- fused CSR aggregate + RK4 stage ----------
// 8 threads/node, float4 (4 channels) each.
// pre = dinv[d] * (sum_{e in CSR[d]} hs[src] + hs[d]); kv = relu(pre+b)[*gate]
// stage 0: x = kv; x2 = kv
// stage 1: ksum = kv;      xt = x + 0.05*kv
// stage 2: ksum += 2*kv;   xt = x + 0.05*kv
// stage 3: ksum += 2*kv;   xt = x + 0.1*kv
// stage 4: x += (0.1/6)*(ksum + kv)
__global__ void agg_rk4(const int* __restrict__ offs, const int* __restrict__ csr,
                        const float* __restrict__ hs, const float* __restrict__ dinv,
                        const float* __restrict__ bias, const float* __restrict__ wt,
                        float t, float* __restrict__ ksum, float* __restrict__ x,
                        float* __restrict__ xt, float* __restrict__ x2, int stage, int N) {
    int tid = blockIdx.x * blockDim.x + threadIdx.x;
    int node = tid >> 3, q = tid & 7;
    if (node >= N) return;
    const float4* hs4 = (const float4*)hs;
    int e0 = offs[node], e1 = offs[node + 1];
    float4 acc = hs4[node * 8 + q]; // self-loop term (pre-scaled once more below)
    for (int e = e0; e < e1; ++e) {
        int s = csr[e];
        float4 v = hs4[s * 8 + q];
        acc.x += v.x; acc.y += v.y; acc.z += v.z; acc.w += v.w;
    }
    float dv = dinv[node];
    float4 bb = *(const float4*)(bias + q * 4);
    float4 kv;
    kv.x = fmaxf(acc.x * dv + bb.x, 0.0f);
    kv.y = fmaxf(acc.y * dv + bb.y, 0.0f);
    kv.z = fmaxf(acc.z * dv + bb.z, 0.0f);
    kv.w = fmaxf(acc.w * dv + bb.w, 0.0f);
    if (wt) {
        float4 w = *(const float4*)(wt + q * 4);
        kv.x *= 1.0f / (1.0f + expf(-t * w.x));
        kv.y *= 1.0f / (1.0f + expf(-t * w.y));
        kv.z *= 1.0f / (1.0f + expf(-t * w.z));
        kv.w *= 1.0f / (1.0f + expf(-t * w.w));
    }
    int i = node * 8 + q;
    if (stage == 0) {
        ((float4*)x)[i] = kv;
        ((float4*)x2)[i] = kv;
        return;
    }
    if (stage == 4) {
        float4 ks = ((const float4*)ksum)[i];
        float4 xv = ((float4*)x)[i];
        const float cc = 0.1f / 6.0f;
        xv.x += cc * (ks.x + kv.x);
        xv.y += cc * (ks.y + kv.y);
        xv.z += cc * (ks.z + kv.z);
        xv.w += cc * (ks.w + kv.w);
        ((float4*)x)[i] = xv;
        return;
    }
    float a = (stage == 3) ? 0.1f : 0.05f;
    float4 xv = ((const float4*)x)[i];
    float4 xo;
    xo.x = xv.x + a * kv.x;
    xo.y = xv.y + a * kv.y;
    xo.z = xv.z + a * kv.z;
    xo.w = xv.w + a * kv.w;
    ((float4*)xt)[i] = xo;
    if (stage == 1) {
        ((float4*)ksum)[i] = kv;
    } else {
        float4 ks = ((const float4*)ksum)[i];
        ks.x += 2.0f * kv.x;
        ks.y += 2.0f * kv.y;
        ks.z += 2.0f * kv.z;
        ks.w += 2.0f * kv.w;
        ((float4*)ksum)[i] = ks;
    }
}

// ---------- combine + layernorm ----------

__global__ void combine_kernel(const float* __restrict__ zp, const float* __restrict__ zn,
                               const float* __restrict__ Wc, const float* __restrict__ bc,
                               const float* __restrict__ g, const float* __restrict__ be,
                               float* __restrict__ out, int N) {
    __shared__ float Ws[64][32];
    __shared__ float zs[8][64];
    int tid = threadIdx.x;
    for (int i = tid; i < 64 * 32; i += TPB) Ws[i >> 5][i & 31] = Wc[i];
    int base = blockIdx.x * 8;
    {
        int r = tid >> 5, c = tid & 31;
        int gr = base + r;
        zs[r][c] = (gr < N) ? zp[gr * 32 + c] : 0.0f;
        zs[r][32 + c] = (gr < N) ? zn[gr * 32 + c] : 0.0f;
    }
    __syncthreads();
    int row = tid >> 5, c = tid & 31;
    int gr = base + row;
    float acc = bc[c];
#pragma unroll
    for (int k = 0; k < 64; ++k) acc += zs[row][k] * Ws[k][c];
    float s = acc, sq = acc * acc;
#pragma unroll
    for (int off = 16; off; off >>= 1) {
        s += __shfl_xor(s, off, 32);
        sq += __shfl_xor(sq, off, 32);
    }
    float mu = s * (1.0f / 32.0f);
    float var = sq * (1.0f / 32.0f) - mu * mu;
    float y = (acc - mu) * rsqrtf(var + 1e-5f) * g[c] + be[c];
    if (gr < N) out[gr * 32 + c] = y;
}

// ---------- host orchestration ----------

extern "C" void kernel_launch(void* const* d_in, const int* in_sizes, int n_in,
                              void* d_out, int out_size, void* d_ws, size_t ws_size,
                              hipStream_t stream) {
    const float* H_t = (const float*)d_in[0];
    const int* Apos = (const int*)d_in[1];
    const int* Aneg = (const int*)d_in[2];
    const int* dApos = (const int*)d_in[3];
    const int* dAneg = (const int*)d_in[4];
    const float* W_init = (const float*)d_in[5];
    const float* b_init = (const float*)d_in[6];
    const float* W_pos = (const float*)d_in[7];
    const float* b_pos = (const float*)d_in[8];
    const float* wt_pos = (const float*)d_in[9];
    const float* W_neg = (const float*)d_in[10];
    const float* b_neg = (const float*)d_in[11];
    const float* wt_neg = (const float*)d_in[12];
    const float* W_comb = (const float*)d_in[13];
    const float* b_comb = (const float*)d_in[14];
    const float* ln_g = (const float*)d_in[15];
    const float* ln_b = (const float*)d_in[16];

    const int N = in_sizes[0] / 128;
    const int E1 = in_sizes[1] / 2;
    const int E2 = in_sizes[2] / 2;
    const int DE1 = in_sizes[3] / 2;
    const int DE2 = in_sizes[4] / 2;

    const int* Apos_src = Apos, * Apos_dst = Apos + E1;
    const int* Aneg_src = Aneg, * Aneg_dst = Aneg + E2;
    const int* dApos_src = dApos, * dApos_dst = dApos + DE1;
    const int* dAneg_src = dAneg, * dAneg_dst = dAneg + DE2;

    const int n32 = N * 32;

    // ---- workspace layout ----
    float* ws = (float*)d_ws;
    float* x_pos = ws;              // N*32
    float* x_neg = x_pos + n32;     // N*32
    float* hs = x_neg + n32;        // N*32
    float* xt = hs + n32;           // N*32
    float* ksum = xt + n32;         // N*32
    float* dinv_all = ksum + n32;   // N
    float* dinv_pos = dinv_all + N; // N
    float* dinv_neg = dinv_pos + N; // N
    int* ip = (int*)(dinv_neg + N);
    int* offs_all = ip;                 // N+1
    int* offs_pos = offs_all + (N + 1); // N+1
    int* offs_neg = offs_pos + (N + 1); // N+1
    int* csr_all = offs_neg + (N + 1);  // E1+E2
    int* csr_pos = csr_all + (E1 + E2); // DE1
    int* csr_neg = csr_pos + DE1;       // DE2
    int* cnt = csr_neg + DE2;           // N
    int* cursor = cnt + N;              // N
    int* bsums = cursor + N;            // SCAN_T

    dim3 blk(TPB);
    auto gblk = [](int n) { return dim3((n + TPB - 1) / TPB); };
    dim3 grid_rows((N + 7) / 8);
    dim3 grid_nodes((N * 8 + TPB - 1) / TPB);
    const int nb = (N + SCAN_T - 1) / SCAN_T;

    // ---- build CSR + dinv for each graph ----
    auto build = [&](const int* s1, const int* d1, int e1, const int* s2, const int* d2, int e2,
                     int* offs, int* csr, float* dinv) {
        hipMemsetAsync(cnt, 0, N * sizeof(int), stream);
        count_dst<<<gblk(e1), blk, 0, stream>>>(d1, e1, cnt);
        if (d2) count_dst<<<gblk(e2), blk, 0, stream>>>(d2, e2, cnt);
        dinv_from_cnt<<<gblk(N), blk, 0, stream>>>(cnt, dinv, N);
        scan_block<<<nb, SCAN_T, 0, stream>>>(cnt, N, offs, bsums);
        scan_sums<<<1, SCAN_T, 0, stream>>>(bsums, nb);
        scan_add<<<gblk(N), blk, 0, stream>>>(offs, bsums, N, e1 + e2);
        hipMemsetAsync(cursor, 0, N * sizeof(int), stream);
        fill_csr<<<gblk(e1), blk, 0, stream>>>(s1, d1, e1, offs, cursor, csr);
        if (s2) fill_csr<<<gblk(e2), blk, 0, stream>>>(s2, d2, e2, offs, cursor, csr);
    };

    build(Apos_src, Apos_dst, E1, Aneg_src, Aneg_dst, E2, offs_all, csr_all, dinv_all);
    build(dApos_src, dApos_dst, DE1, nullptr, nullptr, 0, offs_pos, csr_pos, dinv_pos);
    build(dAneg_src, dAneg_dst, DE2, nullptr, nullptr, 0, offs_neg, csr_neg, dinv_neg);

    // ---- init GCN: H0 = relu(gcn(H_t)) -> x_pos, x_neg ----
    mm128_kernel<<<grid_rows, blk, 0, stream>>>(H_t, W_init, dinv_all, hs, N);
    agg_rk4<<<grid_nodes, blk, 0, stream>>>(offs_all, csr_all, hs, dinv_all, b_init, nullptr,
                                            0.0f, nullptr, x_pos, nullptr, x_neg, 0, N);

    // ---- two ODEs ----
    for (int ode = 0; ode < 2; ++ode) {
        float* x = ode ? x_neg : x_pos;
        const float* W = ode ? W_neg : W_pos;
        const float* b = ode ? b_neg : b_pos;
        const float* wt = ode ? wt_neg : wt_pos;
        const float* dinv = ode ? dinv_neg : dinv_pos;
        const int* offs = ode ? offs_neg : offs_pos;
        const int* csr = ode ? csr_neg : csr_pos;

        for (int s = 0; s < 10; ++s) {
            float t0 = 0.1f * (float)s;
            mm32_kernel<<<grid_rows, blk, 0, stream>>>(x, W, dinv, hs, N);
            agg_rk4<<<grid_nodes, blk, 0, stream>>>(offs, csr, hs, dinv, b, wt, t0,
                                                    ksum, x, xt, nullptr, 1, N);
            mm32_kernel<<<grid_rows, blk, 0, stream>>>(xt, W, dinv, hs, N);
            agg_rk4<<<grid_nodes, blk, 0, stream>>>(offs, csr, hs, dinv, b, wt, t0 + 0.05f,
                                                    ksum, x, xt, nullptr, 2, N);
            mm32_kernel<<<grid_rows, blk, 0, stream>>>(xt, W, dinv, hs, N);
            agg_rk4<<<grid_nodes, blk, 0, stream>>>(offs, csr, hs, dinv, b, wt, t0 + 0.05f,
                                                    ksum, x, xt, nullptr, 3, N);
            mm32_kernel<<<grid_rows, blk, 0, stream>>>(xt, W, dinv, hs, N);
            agg_rk4<<<grid_nodes, blk, 0, stream>>>(offs, csr, hs, dinv, b, wt, t0 + 0.1f,
                                                    ksum, x, nullptr, nullptr, 4, N);
        }
    }

    // ---- combine + layernorm ----
    combine_kernel<<<grid_rows, blk, 0, stream>>>(x_pos, x_neg, W_comb, b_comb, ln_g, ln_b,
                                                  (float*)d_out, N);
}

// Round 3
// 3045.867 us; speedup vs baseline: 9.8394x; 1.4751x over previous
//
#include <hip/hip_runtime.h>
#include <math.h>

// DynamiSE: GCN + 2x RK4 neural ODE + combine/LN.
// R1: CSR gather, coef folded into matmul (hs = dinv * x@W), scatter+finish fused.
// R2: mm32 fused into agg epilogue (LDS-staged xt @ W), xt buffer eliminated,
//     hs double-buffered, gather loop unrolled x4 for MLP.

#define TPB 256
#define SCAN_T 1024

// ---------- CSR build ----------

__global__ void count_dst(const int* __restrict__ dst, int e, int* __restrict__ cnt) {
    int i = blockIdx.x * blockDim.x + threadIdx.x;
    if (i < e) atomicAdd(&cnt[dst[i]], 1);
}

__global__ void dinv_from_cnt(const int* __restrict__ cnt, float* __restrict__ dinv, int n) {
    int i = blockIdx.x * blockDim.x + threadIdx.x;
    if (i < n) dinv[i] = rsqrtf(1.0f + (float)cnt[i]);
}

__global__ void scan_block(const int* __restrict__ in, int n, int* __restrict__ out,
                           int* __restrict__ bsums) {
    __shared__ int sh[SCAN_T];
    int tx = threadIdx.x;
    int g = blockIdx.x * SCAN_T + tx;
    int v = (g < n) ? in[g] : 0;
    sh[tx] = v;
    __syncthreads();
    for (int off = 1; off < SCAN_T; off <<= 1) {
        int t = (tx >= off) ? sh[tx - off] : 0;
        __syncthreads();
        sh[tx] += t;
        __syncthreads();
    }
    if (g < n) out[g] = sh[tx] - v; // exclusive
    if (tx == SCAN_T - 1) bsums[blockIdx.x] = sh[tx];
}

__global__ void scan_sums(int* __restrict__ bsums, int nb) {
    __shared__ int sh[SCAN_T];
    int tx = threadIdx.x;
    int v = (tx < nb) ? bsums[tx] : 0;
    sh[tx] = v;
    __syncthreads();
    for (int off = 1; off < SCAN_T; off <<= 1) {
        int t = (tx >= off) ? sh[tx - off] : 0;
        __syncthreads();
        sh[tx] += t;
        __syncthreads();
    }
    if (tx < nb) bsums[tx] = sh[tx] - v;
}

__global__ void scan_add(int* __restrict__ offs, const int* __restrict__ bsums, int n, int total) {
    int g = blockIdx.x * blockDim.x + threadIdx.x;
    if (g < n) offs[g] += bsums[g >> 10]; // SCAN_T=1024 partitioning
    if (g == 0) offs[n] = total;
}

__global__ void fill_csr(const int* __restrict__ src, const int* __restrict__ dst, int E,
                         const int* __restrict__ offs, int* __restrict__ cursor,
                         int* __restrict__ csr) {
    int e = blockIdx.x * blockDim.x + threadIdx.x;
    if (e >= E) return;
    int d = dst[e];
    int pos = offs[d] + atomicAdd(&cursor[d], 1);
    csr[pos] = src[e];
}

// ---------- seed matmuls: hs = dinv * (x @ W) ----------

__global__ void mm32_kernel(const float* __restrict__ x, const float* __restrict__ W,
                            const float* __restrict__ dinv, float* __restrict__ hs, int N) {
    __shared__ float Ws[32][32];
    __shared__ float xs[8][32];
    int tid = threadIdx.x;
    for (int i = tid; i < 32 * 32; i += TPB) Ws[i >> 5][i & 31] = W[i];
    int base = blockIdx.x * 8;
    {
        int idx = base * 32 + tid;
        xs[tid >> 5][tid & 31] = (idx < N * 32) ? x[idx] : 0.0f;
    }
    __syncthreads();
    int row = tid >> 5, c = tid & 31;
    int gr = base + row;
    float acc = 0.0f;
#pragma unroll
    for (int k = 0; k < 32; ++k) acc += xs[row][k] * Ws[k][c];
    if (gr < N) hs[gr * 32 + c] = acc * dinv[gr];
}

__global__ void mm128_kernel(const float* __restrict__ x, const float* __restrict__ W,
                             const float* __restrict__ dinv, float* __restrict__ hs, int N) {
    __shared__ float Ws[128][32]; // 16 KB
    __shared__ float xs[8][128];  // 4 KB
    int tid = threadIdx.x;
    for (int i = tid; i < 128 * 32; i += TPB) Ws[i >> 5][i & 31] = W[i];
    int base = blockIdx.x * 8;
    for (int i = tid; i < 8 * 128; i += TPB) {
        int idx = base * 128 + i;
        xs[i >> 7][i & 127] = (idx < N * 128) ? x[idx] : 0.0f;
    }
    __syncthreads();
    int row = tid >> 5, c = tid & 31;
    int gr = base + row;
    float acc = 0.0f;
#pragma unroll
    for (int k = 0; k < 128; ++k) acc += xs[row][k] * Ws[k][c];
    if (gr < N) hs[gr * 32 + c] = acc * dinv[gr];
}

// ---------- fused CSR aggregate + RK4 stage + next-stage matmul ----------
// 8 lanes/node, float4 channels each; 32 nodes/block.
// pre = dinv[d]*(sum hs_in[src] + hs_in[d]); kv = relu(pre+b)[*sigmoid(t*wt)]
// stage 0: x=kv; x2=kv;                     xrow=kv
// stage 1: ksum=kv;                          xrow=x+0.05*kv
// stage 2: ksum+=2kv;                        xrow=x+0.05*kv
// stage 3: ksum+=2kv;                        xrow=x+0.1*kv
// stage 4: x+=(0.1/6)*(ksum+kv);             xrow=x
// if do_mm: hs_out[node] = dinv_next[node] * (xrow @ Wnext)
__global__ __launch_bounds__(TPB) void agg_rk4_mm(
    const int* __restrict__ offs, const int* __restrict__ csr,
    const float* __restrict__ hs_in, const float* __restrict__ dinv_g,
    const float* __restrict__ bias, const float* __restrict__ wt, float t,
    float* __restrict__ ksum, float* __restrict__ x, float* __restrict__ x2,
    const float* __restrict__ Wnext, const float* __restrict__ dinv_next,
    float* __restrict__ hs_out, int stage, int do_mm, int N)
{
    __shared__ float Ws[32][32];  // 4 KB
    __shared__ float xts[32][36]; // 4.5 KB (pad to 36 for bank spread)
    int tid = threadIdx.x;
    int lnode = tid >> 3, q = tid & 7;
    int node = blockIdx.x * 32 + lnode;
    bool valid = node < N;

    if (do_mm) {
        for (int i = tid; i < 32 * 32; i += TPB) Ws[i >> 5][i & 31] = Wnext[i];
    }

    float4 xrow = make_float4(0.f, 0.f, 0.f, 0.f);
    if (valid) {
        const float4* hs4 = (const float4*)hs_in;
        int e0 = offs[node], e1 = offs[node + 1];
        float4 acc = hs4[node * 8 + q]; // self-loop term
        int e = e0;
        for (; e + 4 <= e1; e += 4) {
            int s0 = csr[e], s1 = csr[e + 1], s2 = csr[e + 2], s3 = csr[e + 3];
            float4 v0 = hs4[s0 * 8 + q];
            float4 v1 = hs4[s1 * 8 + q];
            float4 v2 = hs4[s2 * 8 + q];
            float4 v3 = hs4[s3 * 8 + q];
            acc.x += (v0.x + v1.x) + (v2.x + v3.x);
            acc.y += (v0.y + v1.y) + (v2.y + v3.y);
            acc.z += (v0.z + v1.z) + (v2.z + v3.z);
            acc.w += (v0.w + v1.w) + (v2.w + v3.w);
        }
        for (; e < e1; ++e) {
            int s = csr[e];
            float4 v = hs4[s * 8 + q];
            acc.x += v.x; acc.y += v.y; acc.z += v.z; acc.w += v.w;
        }
        float dv = dinv_g[node];
        float4 bb = *(const float4*)(bias + q * 4);
        float4 kv;
        kv.x = fmaxf(acc.x * dv + bb.x, 0.0f);
        kv.y = fmaxf(acc.y * dv + bb.y, 0.0f);
        kv.z = fmaxf(acc.z * dv + bb.z, 0.0f);
        kv.w = fmaxf(acc.w * dv + bb.w, 0.0f);
        if (wt) {
            float4 w = *(const float4*)(wt + q * 4);
            kv.x *= 1.0f / (1.0f + expf(-t * w.x));
            kv.y *= 1.0f / (1.0f + expf(-t * w.y));
            kv.z *= 1.0f / (1.0f + expf(-t * w.z));
            kv.w *= 1.0f / (1.0f + expf(-t * w.w));
        }
        int idx = node * 8 + q;
        if (stage == 0) {
            ((float4*)x)[idx] = kv;
            ((float4*)x2)[idx] = kv;
            xrow = kv;
        } else if (stage == 4) {
            float4 ks = ((const float4*)ksum)[idx];
            float4 xv = ((float4*)x)[idx];
            const float cc = 0.1f / 6.0f;
            xv.x += cc * (ks.x + kv.x);
            xv.y += cc * (ks.y + kv.y);
            xv.z += cc * (ks.z + kv.z);
            xv.w += cc * (ks.w + kv.w);
            ((float4*)x)[idx] = xv;
            xrow = xv;
        } else {
            float a = (stage == 3) ? 0.1f : 0.05f;
            float4 xv = ((const float4*)x)[idx];
            xrow.x = xv.x + a * kv.x;
            xrow.y = xv.y + a * kv.y;
            xrow.z = xv.z + a * kv.z;
            xrow.w = xv.w + a * kv.w;
            if (stage == 1) {
                ((float4*)ksum)[idx] = kv;
            } else {
                float4 ks = ((const float4*)ksum)[idx];
                ks.x += 2.0f * kv.x;
                ks.y += 2.0f * kv.y;
                ks.z += 2.0f * kv.z;
                ks.w += 2.0f * kv.w;
                ((float4*)ksum)[idx] = ks;
            }
        }
    }

    if (do_mm) {
        if (valid) *(float4*)&xts[lnode][q * 4] = xrow;
        __syncthreads();
        if (valid) {
            float4 accm = make_float4(0.f, 0.f, 0.f, 0.f);
#pragma unroll
            for (int k = 0; k < 32; ++k) {
                float xv = xts[lnode][k];
                float4 w = *(const float4*)&Ws[k][q * 4];
                accm.x += xv * w.x;
                accm.y += xv * w.y;
                accm.z += xv * w.z;
                accm.w += xv * w.w;
            }
            float dn = dinv_next[node];
            accm.x *= dn; accm.y *= dn; accm.z *= dn; accm.w *= dn;
            ((float4*)hs_out)[node * 8 + q] = accm;
        }
    }
}

// ---------- combine + layernorm ----------

__global__ void combine_kernel(const float* __restrict__ zp, const float* __restrict__ zn,
                               const float* __restrict__ Wc, const float* __restrict__ bc,
                               const float* __restrict__ g, const float* __restrict__ be,
                               float* __restrict__ out, int N) {
    __shared__ float Ws[64][32];
    __shared__ float zs[8][64];
    int tid = threadIdx.x;
    for (int i = tid; i < 64 * 32; i += TPB) Ws[i >> 5][i & 31] = Wc[i];
    int base = blockIdx.x * 8;
    {
        int r = tid >> 5, c = tid & 31;
        int gr = base + r;
        zs[r][c] = (gr < N) ? zp[gr * 32 + c] : 0.0f;
        zs[r][32 + c] = (gr < N) ? zn[gr * 32 + c] : 0.0f;
    }
    __syncthreads();
    int row = tid >> 5, c = tid & 31;
    int gr = base + row;
    float acc = bc[c];
#pragma unroll
    for (int k = 0; k < 64; ++k) acc += zs[row][k] * Ws[k][c];
    float s = acc, sq = acc * acc;
#pragma unroll
    for (int off = 16; off; off >>= 1) {
        s += __shfl_xor(s, off, 32);
        sq += __shfl_xor(sq, off, 32);
    }
    float mu = s * (1.0f / 32.0f);
    float var = sq * (1.0f / 32.0f) - mu * mu;
    float y = (acc - mu) * rsqrtf(var + 1e-5f) * g[c] + be[c];
    if (gr < N) out[gr * 32 + c] = y;
}

// ---------- host orchestration ----------

extern "C" void kernel_launch(void* const* d_in, const int* in_sizes, int n_in,
                              void* d_out, int out_size, void* d_ws, size_t ws_size,
                              hipStream_t stream) {
    const float* H_t = (const float*)d_in[0];
    const int* Apos = (const int*)d_in[1];
    const int* Aneg = (const int*)d_in[2];
    const int* dApos = (const int*)d_in[3];
    const int* dAneg = (const int*)d_in[4];
    const float* W_init = (const float*)d_in[5];
    const float* b_init = (const float*)d_in[6];
    const float* W_pos = (const float*)d_in[7];
    const float* b_pos = (const float*)d_in[8];
    const float* wt_pos = (const float*)d_in[9];
    const float* W_neg = (const float*)d_in[10];
    const float* b_neg = (const float*)d_in[11];
    const float* wt_neg = (const float*)d_in[12];
    const float* W_comb = (const float*)d_in[13];
    const float* b_comb = (const float*)d_in[14];
    const float* ln_g = (const float*)d_in[15];
    const float* ln_b = (const float*)d_in[16];

    const int N = in_sizes[0] / 128;
    const int E1 = in_sizes[1] / 2;
    const int E2 = in_sizes[2] / 2;
    const int DE1 = in_sizes[3] / 2;
    const int DE2 = in_sizes[4] / 2;

    const int* Apos_src = Apos, * Apos_dst = Apos + E1;
    const int* Aneg_src = Aneg, * Aneg_dst = Aneg + E2;
    const int* dApos_src = dApos, * dApos_dst = dApos + DE1;
    const int* dAneg_src = dAneg, * dAneg_dst = dAneg + DE2;

    const int n32 = N * 32;

    // ---- workspace layout ----
    float* ws = (float*)d_ws;
    float* x_pos = ws;              // N*32
    float* x_neg = x_pos + n32;     // N*32
    float* hs_a = x_neg + n32;      // N*32
    float* hs_b = hs_a + n32;       // N*32
    float* ksum = hs_b + n32;       // N*32
    float* dinv_all = ksum + n32;   // N
    float* dinv_pos = dinv_all + N; // N
    float* dinv_neg = dinv_pos + N; // N
    int* ip = (int*)(dinv_neg + N);
    int* offs_all = ip;                 // N+1
    int* offs_pos = offs_all + (N + 1); // N+1
    int* offs_neg = offs_pos + (N + 1); // N+1
    int* csr_all = offs_neg + (N + 1);  // E1+E2
    int* csr_pos = csr_all + (E1 + E2); // DE1
    int* csr_neg = csr_pos + DE1;       // DE2
    int* cnt = csr_neg + DE2;           // N
    int* cursor = cnt + N;              // N
    int* bsums = cursor + N;            // SCAN_T

    dim3 blk(TPB);
    auto gblk = [](int n) { return dim3((n + TPB - 1) / TPB); };
    dim3 grid_rows((N + 7) / 8);
    dim3 grid_fused((N + 31) / 32);
    const int nb = (N + SCAN_T - 1) / SCAN_T;

    // ---- build CSR + dinv for each graph ----
    auto build = [&](const int* s1, const int* d1, int e1, const int* s2, const int* d2, int e2,
                     int* offs, int* csr, float* dinv) {
        hipMemsetAsync(cnt, 0, N * sizeof(int), stream);
        count_dst<<<gblk(e1), blk, 0, stream>>>(d1, e1, cnt);
        if (d2) count_dst<<<gblk(e2), blk, 0, stream>>>(d2, e2, cnt);
        dinv_from_cnt<<<gblk(N), blk, 0, stream>>>(cnt, dinv, N);
        scan_block<<<nb, SCAN_T, 0, stream>>>(cnt, N, offs, bsums);
        scan_sums<<<1, SCAN_T, 0, stream>>>(bsums, nb);
        scan_add<<<gblk(N), blk, 0, stream>>>(offs, bsums, N, e1 + e2);
        hipMemsetAsync(cursor, 0, N * sizeof(int), stream);
        fill_csr<<<gblk(e1), blk, 0, stream>>>(s1, d1, e1, offs, cursor, csr);
        if (s2) fill_csr<<<gblk(e2), blk, 0, stream>>>(s2, d2, e2, offs, cursor, csr);
    };

    build(Apos_src, Apos_dst, E1, Aneg_src, Aneg_dst, E2, offs_all, csr_all, dinv_all);
    build(dApos_src, dApos_dst, DE1, nullptr, nullptr, 0, offs_pos, csr_pos, dinv_pos);
    build(dAneg_src, dAneg_dst, DE2, nullptr, nullptr, 0, offs_neg, csr_neg, dinv_neg);

    // ---- init GCN: H0 = relu(gcn(H_t)) -> x_pos, x_neg; epilogue seeds pos hs ----
    mm128_kernel<<<grid_rows, blk, 0, stream>>>(H_t, W_init, dinv_all, hs_a, N);
    agg_rk4_mm<<<grid_fused, blk, 0, stream>>>(offs_all, csr_all, hs_a, dinv_all, b_init,
                                               nullptr, 0.0f, nullptr, x_pos, x_neg,
                                               W_pos, dinv_pos, hs_b, 0, 1, N);

    // ---- two ODEs ----
    for (int ode = 0; ode < 2; ++ode) {
        float* x = ode ? x_neg : x_pos;
        const float* W = ode ? W_neg : W_pos;
        const float* b = ode ? b_neg : b_pos;
        const float* wt = ode ? wt_neg : wt_pos;
        const float* dinv = ode ? dinv_neg : dinv_pos;
        const int* offs = ode ? offs_neg : offs_pos;
        const int* csr = ode ? csr_neg : csr_pos;

        if (ode == 1) {
            // seed hs for neg ODE (pos ODE was seeded by the init epilogue)
            mm32_kernel<<<grid_rows, blk, 0, stream>>>(x, W, dinv, hs_b, N);
        }

        for (int s = 0; s < 10; ++s) {
            float t0 = 0.1f * (float)s;
            int last = (s == 9) ? 0 : 1;
            // stage1: in=hs_b out=hs_a
            agg_rk4_mm<<<grid_fused, blk, 0, stream>>>(offs, csr, hs_b, dinv, b, wt, t0,
                                                       ksum, x, nullptr, W, dinv, hs_a, 1, 1, N);
            // stage2: in=hs_a out=hs_b
            agg_rk4_mm<<<grid_fused, blk, 0, stream>>>(offs, csr, hs_a, dinv, b, wt, t0 + 0.05f,
                                                       ksum, x, nullptr, W, dinv, hs_b, 2, 1, N);
            // stage3: in=hs_b out=hs_a
            agg_rk4_mm<<<grid_fused, blk, 0, stream>>>(offs, csr, hs_b, dinv, b, wt, t0 + 0.05f,
                                                       ksum, x, nullptr, W, dinv, hs_a, 3, 1, N);
            // stage4: in=hs_a out=hs_b (skip mm on last step)
            agg_rk4_mm<<<grid_fused, blk, 0, stream>>>(offs, csr, hs_a, dinv, b, wt, t0 + 0.1f,
                                                       ksum, x, nullptr, W, dinv, hs_b, 4, last, N);
        }
    }

    // ---- combine + layernorm ----
    combine_kernel<<<grid_rows, blk, 0, stream>>>(x_pos, x_neg, W_comb, b_comb, ln_g, ln_b,
                                                  (float*)d_out, N);
}

// Round 4
// 2716.150 us; speedup vs baseline: 11.0338x; 1.1214x over previous
//
#include <hip/hip_runtime.h>
#include <math.h>

// DynamiSE: GCN + 2x RK4 neural ODE + combine/LN.
// R1: CSR gather, coef folded into matmul (hs = dinv * x@W).
// R2: mm32 fused into agg epilogue, hs double-buffered.
// R3: both ODEs merged into one dispatch per RK4 stage (block-range split),
//     CSR indices LDS-staged per block (contiguous range per 32 nodes),
//     runtime ws_size check with sequential fallback.

#define TPB 256
#define SCAN_T 1024
#define IDX_CAP 2048

// ---------- CSR build ----------

__global__ void count_dst(const int* __restrict__ dst, int e, int* __restrict__ cnt) {
    int i = blockIdx.x * blockDim.x + threadIdx.x;
    if (i < e) atomicAdd(&cnt[dst[i]], 1);
}

__global__ void dinv_from_cnt(const int* __restrict__ cnt, float* __restrict__ dinv, int n) {
    int i = blockIdx.x * blockDim.x + threadIdx.x;
    if (i < n) dinv[i] = rsqrtf(1.0f + (float)cnt[i]);
}

__global__ void scan_block(const int* __restrict__ in, int n, int* __restrict__ out,
                           int* __restrict__ bsums) {
    __shared__ int sh[SCAN_T];
    int tx = threadIdx.x;
    int g = blockIdx.x * SCAN_T + tx;
    int v = (g < n) ? in[g] : 0;
    sh[tx] = v;
    __syncthreads();
    for (int off = 1; off < SCAN_T; off <<= 1) {
        int t = (tx >= off) ? sh[tx - off] : 0;
        __syncthreads();
        sh[tx] += t;
        __syncthreads();
    }
    if (g < n) out[g] = sh[tx] - v; // exclusive
    if (tx == SCAN_T - 1) bsums[blockIdx.x] = sh[tx];
}

__global__ void scan_sums(int* __restrict__ bsums, int nb) {
    __shared__ int sh[SCAN_T];
    int tx = threadIdx.x;
    int v = (tx < nb) ? bsums[tx] : 0;
    sh[tx] = v;
    __syncthreads();
    for (int off = 1; off < SCAN_T; off <<= 1) {
        int t = (tx >= off) ? sh[tx - off] : 0;
        __syncthreads();
        sh[tx] += t;
        __syncthreads();
    }
    if (tx < nb) bsums[tx] = sh[tx] - v;
}

__global__ void scan_add(int* __restrict__ offs, const int* __restrict__ bsums, int n, int total) {
    int g = blockIdx.x * blockDim.x + threadIdx.x;
    if (g < n) offs[g] += bsums[g >> 10]; // SCAN_T=1024 partitioning
    if (g == 0) offs[n] = total;
}

__global__ void fill_csr(const int* __restrict__ src, const int* __restrict__ dst, int E,
                         const int* __restrict__ offs, int* __restrict__ cursor,
                         int* __restrict__ csr) {
    int e = blockIdx.x * blockDim.x + threadIdx.x;
    if (e >= E) return;
    int d = dst[e];
    int pos = offs[d] + atomicAdd(&cursor[d], 1);
    csr[pos] = src[e];
}

// ---------- seed matmuls: hs = dinv * (x @ W) ----------

__global__ void mm32_kernel(const float* __restrict__ x, const float* __restrict__ W,
                            const float* __restrict__ dinv, float* __restrict__ hs, int N) {
    __shared__ float Ws[32][32];
    __shared__ float xs[8][32];
    int tid = threadIdx.x;
    for (int i = tid; i < 32 * 32; i += TPB) Ws[i >> 5][i & 31] = W[i];
    int base = blockIdx.x * 8;
    {
        int idx = base * 32 + tid;
        xs[tid >> 5][tid & 31] = (idx < N * 32) ? x[idx] : 0.0f;
    }
    __syncthreads();
    int row = tid >> 5, c = tid & 31;
    int gr = base + row;
    float acc = 0.0f;
#pragma unroll
    for (int k = 0; k < 32; ++k) acc += xs[row][k] * Ws[k][c];
    if (gr < N) hs[gr * 32 + c] = acc * dinv[gr];
}

__global__ void mm128_kernel(const float* __restrict__ x, const float* __restrict__ W,
                             const float* __restrict__ dinv, float* __restrict__ hs, int N) {
    __shared__ float Ws[128][32]; // 16 KB
    __shared__ float xs[8][128];  // 4 KB
    int tid = threadIdx.x;
    for (int i = tid; i < 128 * 32; i += TPB) Ws[i >> 5][i & 31] = W[i];
    int base = blockIdx.x * 8;
    for (int i = tid; i < 8 * 128; i += TPB) {
        int idx = base * 128 + i;
        xs[i >> 7][i & 127] = (idx < N * 128) ? x[idx] : 0.0f;
    }
    __syncthreads();
    int row = tid >> 5, c = tid & 31;
    int gr = base + row;
    float acc = 0.0f;
#pragma unroll
    for (int k = 0; k < 128; ++k) acc += xs[row][k] * Ws[k][c];
    if (gr < N) hs[gr * 32 + c] = acc * dinv[gr];
}

// ---------- fused CSR aggregate + RK4 stage + next matmul (2 jobs / dispatch) ----------

struct Job {
    const int* offs; const int* csr;
    const float* hs_in; float* hs_out;
    const float* dinv; const float* dinv_next;
    const float* bias; const float* wt;
    float* ksum; float* x;
    const float* W;
};

// 8 lanes/node, 32 nodes/block. blocks [0,nbp) -> jp, [nbp,..) -> jn.
// pre = dinv[d]*(sum hs_in[src] + hs_in[d]); kv = relu(pre+b)[*sigmoid(t*wt)]
// stage 0: x=kv; x2=kv;                xrow=kv
// stage 1: ksum=kv;                    xrow=x+0.05*kv
// stage 2: ksum+=2kv;                  xrow=x+0.05*kv
// stage 3: ksum+=2kv;                  xrow=x+0.1*kv
// stage 4: x+=(0.1/6)*(ksum+kv);       xrow=x
// if do_mm: hs_out[node] = dinv_next[node] * (xrow @ W)
__global__ __launch_bounds__(TPB) void agg_stage(Job jp, Job jn, int nbp, float t,
                                                 int stage, int do_mm, float* __restrict__ x2,
                                                 int N) {
    __shared__ float Ws[32][32];  // 4 KB
    __shared__ float xts[32][36]; // 4.5 KB (stride 36: conflict-free mm reads)
    __shared__ int sidx[IDX_CAP]; // 8 KB
    __shared__ int soffs[33];

    bool isP = blockIdx.x < nbp;
    const Job& J = isP ? jp : jn;
    int bid = isP ? blockIdx.x : (blockIdx.x - nbp);
    int nbase = bid * 32;
    int tid = threadIdx.x;
    int lnode = tid >> 3, q = tid & 7;
    int node = nbase + lnode;
    bool valid = node < N;

    if (do_mm) {
        for (int i = tid; i < 32 * 32; i += TPB) Ws[i >> 5][i & 31] = J.W[i];
    }
    int nend = nbase + 32; if (nend > N) nend = N;
    int e_lo = J.offs[nbase];
    int e_hi = J.offs[nend];
    int cnt = e_hi - e_lo;
    int staged = cnt < IDX_CAP ? cnt : IDX_CAP;
    for (int i = tid; i < staged; i += TPB) sidx[i] = J.csr[e_lo + i];
    if (tid < 33) {
        int ix = nbase + tid; if (ix > N) ix = N;
        soffs[tid] = J.offs[ix];
    }
    __syncthreads();

    float4 xrow = make_float4(0.f, 0.f, 0.f, 0.f);
    if (valid) {
        const float4* hs4 = (const float4*)J.hs_in;
        int r0 = soffs[lnode] - e_lo;
        int r1 = soffs[lnode + 1] - e_lo;
        float4 acc = hs4[node * 8 + q]; // self-loop
        int i = r0;
        int lim = r1 < staged ? r1 : staged;
        for (; i + 4 <= lim; i += 4) {
            int s0 = sidx[i], s1 = sidx[i + 1], s2 = sidx[i + 2], s3 = sidx[i + 3];
            float4 v0 = hs4[s0 * 8 + q];
            float4 v1 = hs4[s1 * 8 + q];
            float4 v2 = hs4[s2 * 8 + q];
            float4 v3 = hs4[s3 * 8 + q];
            acc.x += (v0.x + v1.x) + (v2.x + v3.x);
            acc.y += (v0.y + v1.y) + (v2.y + v3.y);
            acc.z += (v0.z + v1.z) + (v2.z + v3.z);
            acc.w += (v0.w + v1.w) + (v2.w + v3.w);
        }
        for (; i < lim; ++i) {
            int s = sidx[i];
            float4 v = hs4[s * 8 + q];
            acc.x += v.x; acc.y += v.y; acc.z += v.z; acc.w += v.w;
        }
        for (; i < r1; ++i) { // LDS overflow tail (init graph only)
            int s = J.csr[e_lo + i];
            float4 v = hs4[s * 8 + q];
            acc.x += v.x; acc.y += v.y; acc.z += v.z; acc.w += v.w;
        }
        float dv = J.dinv[node];
        float4 bb = *(const float4*)(J.bias + q * 4);
        float4 kv;
        kv.x = fmaxf(acc.x * dv + bb.x, 0.0f);
        kv.y = fmaxf(acc.y * dv + bb.y, 0.0f);
        kv.z = fmaxf(acc.z * dv + bb.z, 0.0f);
        kv.w = fmaxf(acc.w * dv + bb.w, 0.0f);
        if (J.wt) {
            float4 w = *(const float4*)(J.wt + q * 4);
            kv.x *= 1.0f / (1.0f + expf(-t * w.x));
            kv.y *= 1.0f / (1.0f + expf(-t * w.y));
            kv.z *= 1.0f / (1.0f + expf(-t * w.z));
            kv.w *= 1.0f / (1.0f + expf(-t * w.w));
        }
        int idx = node * 8 + q;
        if (stage == 0) {
            ((float4*)J.x)[idx] = kv;
            ((float4*)x2)[idx] = kv;
            xrow = kv;
        } else if (stage == 4) {
            float4 ks = ((const float4*)J.ksum)[idx];
            float4 xv = ((float4*)J.x)[idx];
            const float cc = 0.1f / 6.0f;
            xv.x += cc * (ks.x + kv.x);
            xv.y += cc * (ks.y + kv.y);
            xv.z += cc * (ks.z + kv.z);
            xv.w += cc * (ks.w + kv.w);
            ((float4*)J.x)[idx] = xv;
            xrow = xv;
        } else {
            float a = (stage == 3) ? 0.1f : 0.05f;
            float4 xv = ((const float4*)J.x)[idx];
            xrow.x = xv.x + a * kv.x;
            xrow.y = xv.y + a * kv.y;
            xrow.z = xv.z + a * kv.z;
            xrow.w = xv.w + a * kv.w;
            if (stage == 1) {
                ((float4*)J.ksum)[idx] = kv;
            } else {
                float4 ks = ((const float4*)J.ksum)[idx];
                ks.x += 2.0f * kv.x;
                ks.y += 2.0f * kv.y;
                ks.z += 2.0f * kv.z;
                ks.w += 2.0f * kv.w;
                ((float4*)J.ksum)[idx] = ks;
            }
        }
    }

    if (do_mm) {
        if (valid) *(float4*)&xts[lnode][q * 4] = xrow;
        __syncthreads();
        if (valid) {
            float4 accm = make_float4(0.f, 0.f, 0.f, 0.f);
#pragma unroll
            for (int k = 0; k < 32; ++k) {
                float xv = xts[lnode][k];
                float4 w = *(const float4*)&Ws[k][q * 4];
                accm.x += xv * w.x;
                accm.y += xv * w.y;
                accm.z += xv * w.z;
                accm.w += xv * w.w;
            }
            float dn = J.dinv_next[node];
            accm.x *= dn; accm.y *= dn; accm.z *= dn; accm.w *= dn;
            ((float4*)J.hs_out)[node * 8 + q] = accm;
        }
    }
}

// ---------- combine + layernorm ----------

__global__ void combine_kernel(const float* __restrict__ zp, const float* __restrict__ zn,
                               const float* __restrict__ Wc, const float* __restrict__ bc,
                               const float* __restrict__ g, const float* __restrict__ be,
                               float* __restrict__ out, int N) {
    __shared__ float Ws[64][32];
    __shared__ float zs[8][64];
    int tid = threadIdx.x;
    for (int i = tid; i < 64 * 32; i += TPB) Ws[i >> 5][i & 31] = Wc[i];
    int base = blockIdx.x * 8;
    {
        int r = tid >> 5, c = tid & 31;
        int gr = base + r;
        zs[r][c] = (gr < N) ? zp[gr * 32 + c] : 0.0f;
        zs[r][32 + c] = (gr < N) ? zn[gr * 32 + c] : 0.0f;
    }
    __syncthreads();
    int row = tid >> 5, c = tid & 31;
    int gr = base + row;
    float acc = bc[c];
#pragma unroll
    for (int k = 0; k < 64; ++k) acc += zs[row][k] * Ws[k][c];
    float s = acc, sq = acc * acc;
#pragma unroll
    for (int off = 16; off; off >>= 1) {
        s += __shfl_xor(s, off, 32);
        sq += __shfl_xor(sq, off, 32);
    }
    float mu = s * (1.0f / 32.0f);
    float var = sq * (1.0f / 32.0f) - mu * mu;
    float y = (acc - mu) * rsqrtf(var + 1e-5f) * g[c] + be[c];
    if (gr < N) out[gr * 32 + c] = y;
}

// ---------- host orchestration ----------

extern "C" void kernel_launch(void* const* d_in, const int* in_sizes, int n_in,
                              void* d_out, int out_size, void* d_ws, size_t ws_size,
                              hipStream_t stream) {
    const float* H_t = (const float*)d_in[0];
    const int* Apos = (const int*)d_in[1];
    const int* Aneg = (const int*)d_in[2];
    const int* dApos = (const int*)d_in[3];
    const int* dAneg = (const int*)d_in[4];
    const float* W_init = (const float*)d_in[5];
    const float* b_init = (const float*)d_in[6];
    const float* W_pos = (const float*)d_in[7];
    const float* b_pos = (const float*)d_in[8];
    const float* wt_pos = (const float*)d_in[9];
    const float* W_neg = (const float*)d_in[10];
    const float* b_neg = (const float*)d_in[11];
    const float* wt_neg = (const float*)d_in[12];
    const float* W_comb = (const float*)d_in[13];
    const float* b_comb = (const float*)d_in[14];
    const float* ln_g = (const float*)d_in[15];
    const float* ln_b = (const float*)d_in[16];

    const int N = in_sizes[0] / 128;
    const int E1 = in_sizes[1] / 2;
    const int E2 = in_sizes[2] / 2;
    const int DE1 = in_sizes[3] / 2;
    const int DE2 = in_sizes[4] / 2;

    const int* Apos_src = Apos, * Apos_dst = Apos + E1;
    const int* Aneg_src = Aneg, * Aneg_dst = Aneg + E2;
    const int* dApos_src = dApos, * dApos_dst = dApos + DE1;
    const int* dAneg_src = dAneg, * dAneg_dst = dAneg + DE2;

    const size_t n32 = (size_t)N * 32;

    // ---- workspace layout (runtime-sized; merged needs 3 extra big buffers) ----
    // small tail (always): dinv*3, offs*3, csr_pos, csr_neg, cnt, cursor, bsums
    size_t small_f = 3 * (size_t)N;                              // dinv
    size_t small_i = 3 * ((size_t)N + 1) + DE1 + DE2 + 2 * (size_t)N + SCAN_T;
    size_t csr_all_elems = (size_t)E1 + E2;
    bool csr_all_fits = csr_all_elems <= n32; // csr_all aliases ksum_p if it fits
    size_t need_fallback = (5 * n32 + small_f + (csr_all_fits ? 0 : csr_all_elems ? csr_all_elems : 0)) * 4 + small_i * 4;
    size_t need_merged = (8 * n32 + small_f + (csr_all_fits ? 0 : csr_all_elems)) * 4 + small_i * 4;
    bool merged = ws_size >= need_merged + 1024;
    (void)need_fallback;

    float* fp = (float*)d_ws;
    float* x_pos = fp; fp += n32;
    float* x_neg = fp; fp += n32;
    float* hs_pa = fp; fp += n32;
    float* hs_pb = fp; fp += n32;
    float* ksum_p = fp; fp += n32;
    float* hs_na, * hs_nb, * ksum_n;
    if (merged) {
        hs_na = fp; fp += n32;
        hs_nb = fp; fp += n32;
        ksum_n = fp; fp += n32;
    } else {
        hs_na = hs_pa; hs_nb = hs_pb; ksum_n = ksum_p;
    }
    float* dinv_all = fp; fp += N;
    float* dinv_pos = fp; fp += N;
    float* dinv_neg = fp; fp += N;
    int* ipp = (int*)fp;
    int* offs_all = ipp; ipp += N + 1;
    int* offs_pos = ipp; ipp += N + 1;
    int* offs_neg = ipp; ipp += N + 1;
    int* csr_pos = ipp; ipp += DE1;
    int* csr_neg = ipp; ipp += DE2;
    int* cnt = ipp; ipp += N;
    int* cursor = ipp; ipp += N;
    int* bsums = ipp; ipp += SCAN_T;
    // csr_all: aliases ksum_p (ksum first written at stage 1, after last csr_all read)
    int* csr_all = csr_all_fits ? (int*)ksum_p : ipp;

    dim3 blk(TPB);
    auto gblk = [](int n) { return dim3((n + TPB - 1) / TPB); };
    dim3 grid_rows((N + 7) / 8);
    const int nb32 = (N + 31) / 32;
    const int nb = (N + SCAN_T - 1) / SCAN_T;

    // ---- build CSR + dinv for each graph ----
    auto build = [&](const int* s1, const int* d1, int e1, const int* s2, const int* d2, int e2,
                     int* offs, int* csr, float* dinv) {
        hipMemsetAsync(cnt, 0, N * sizeof(int), stream);
        count_dst<<<gblk(e1), blk, 0, stream>>>(d1, e1, cnt);
        if (d2) count_dst<<<gblk(e2), blk, 0, stream>>>(d2, e2, cnt);
        dinv_from_cnt<<<gblk(N), blk, 0, stream>>>(cnt, dinv, N);
        scan_block<<<nb, SCAN_T, 0, stream>>>(cnt, N, offs, bsums);
        scan_sums<<<1, SCAN_T, 0, stream>>>(bsums, nb);
        scan_add<<<gblk(N), blk, 0, stream>>>(offs, bsums, N, e1 + e2);
        hipMemsetAsync(cursor, 0, N * sizeof(int), stream);
        fill_csr<<<gblk(e1), blk, 0, stream>>>(s1, d1, e1, offs, cursor, csr);
        if (s2) fill_csr<<<gblk(e2), blk, 0, stream>>>(s2, d2, e2, offs, cursor, csr);
    };

    build(Apos_src, Apos_dst, E1, Aneg_src, Aneg_dst, E2, offs_all, csr_all, dinv_all);
    build(dApos_src, dApos_dst, DE1, nullptr, nullptr, 0, offs_pos, csr_pos, dinv_pos);
    build(dAneg_src, dAneg_dst, DE2, nullptr, nullptr, 0, offs_neg, csr_neg, dinv_neg);

    // ---- job descriptors ----
    auto mkjob = [](const int* offs, const int* csr, const float* hs_in, float* hs_out,
                    const float* dinv, const float* dinv_next, const float* bias,
                    const float* wt, float* ksum, float* x, const float* W) {
        Job j; j.offs = offs; j.csr = csr; j.hs_in = hs_in; j.hs_out = hs_out;
        j.dinv = dinv; j.dinv_next = dinv_next; j.bias = bias; j.wt = wt;
        j.ksum = ksum; j.x = x; j.W = W; return j;
    };

    // ---- init GCN: H0 = relu(gcn(H_t)) -> x_pos, x_neg; epilogue seeds pos hs ----
    mm128_kernel<<<grid_rows, blk, 0, stream>>>(H_t, W_init, dinv_all, hs_pa, N);
    {
        Job j0 = mkjob(offs_all, csr_all, hs_pa, hs_pb, dinv_all, dinv_pos, b_init,
                       nullptr, nullptr, x_pos, W_pos);
        agg_stage<<<nb32, blk, 0, stream>>>(j0, j0, nb32, 0.0f, 0, 1, x_neg, N);
    }
    // seed hs for neg ODE
    mm32_kernel<<<grid_rows, blk, 0, stream>>>(x_neg, W_neg, dinv_neg, hs_nb, N);

    if (merged) {
        for (int s = 0; s < 10; ++s) {
            float t0 = 0.1f * (float)s;
            int last_mm = (s == 9) ? 0 : 1;
            Job p1 = mkjob(offs_pos, csr_pos, hs_pb, hs_pa, dinv_pos, dinv_pos, b_pos, wt_pos, ksum_p, x_pos, W_pos);
            Job n1 = mkjob(offs_neg, csr_neg, hs_nb, hs_na, dinv_neg, dinv_neg, b_neg, wt_neg, ksum_n, x_neg, W_neg);
            agg_stage<<<2 * nb32, blk, 0, stream>>>(p1, n1, nb32, t0, 1, 1, nullptr, N);
            Job p2 = p1; p2.hs_in = hs_pa; p2.hs_out = hs_pb;
            Job n2 = n1; n2.hs_in = hs_na; n2.hs_out = hs_nb;
            agg_stage<<<2 * nb32, blk, 0, stream>>>(p2, n2, nb32, t0 + 0.05f, 2, 1, nullptr, N);
            agg_stage<<<2 * nb32, blk, 0, stream>>>(p1, n1, nb32, t0 + 0.05f, 3, 1, nullptr, N);
            agg_stage<<<2 * nb32, blk, 0, stream>>>(p2, n2, nb32, t0 + 0.1f, 4, last_mm, nullptr, N);
        }
    } else {
        for (int ode = 0; ode < 2; ++ode) {
            float* x = ode ? x_neg : x_pos;
            const float* W = ode ? W_neg : W_pos;
            const float* b = ode ? b_neg : b_pos;
            const float* wt = ode ? wt_neg : wt_pos;
            const float* dinv = ode ? dinv_neg : dinv_pos;
            const int* offs = ode ? offs_neg : offs_pos;
            const int* csr = ode ? csr_neg : csr_pos;
            if (ode == 1) {
                // re-seed: hs_nb aliases hs_pb which pos ODE clobbered
                mm32_kernel<<<grid_rows, blk, 0, stream>>>(x, W, dinv, hs_pb, N);
            }
            for (int s = 0; s < 10; ++s) {
                float t0 = 0.1f * (float)s;
                int last_mm = (s == 9) ? 0 : 1;
                Job j1 = mkjob(offs, csr, hs_pb, hs_pa, dinv, dinv, b, wt, ksum_p, x, W);
                Job j2 = j1; j2.hs_in = hs_pa; j2.hs_out = hs_pb;
                agg_stage<<<nb32, blk, 0, stream>>>(j1, j1, nb32, t0, 1, 1, nullptr, N);
                agg_stage<<<nb32, blk, 0, stream>>>(j2, j2, nb32, t0 + 0.05f, 2, 1, nullptr, N);
                agg_stage<<<nb32, blk, 0, stream>>>(j1, j1, nb32, t0 + 0.05f, 3, 1, nullptr, N);
                agg_stage<<<nb32, blk, 0, stream>>>(j2, j2, nb32, t0 + 0.1f, 4, last_mm, nullptr, N);
            }
        }
    }

    // ---- combine + layernorm ----
    combine_kernel<<<grid_rows, blk, 0, stream>>>(x_pos, x_neg, W_comb, b_comb, ln_g, ln_b,
                                                  (float*)d_out, N);
}

// Round 6
// 2184.816 us; speedup vs baseline: 13.7172x; 1.2432x over previous
//
#include <hip/hip_runtime.h>
#include <math.h>

// DynamiSE: GCN + 2x RK4 neural ODE + combine/LN.
// R1: CSR gather, coef folded into matmul (hs = dinv * x@W).
// R2: mm32 fused into agg epilogue, hs double-buffered.
// R3: merged pos/neg dispatch, LDS-staged CSR indices.
// R4: fp16 hs (64B gather rows), vec8 lanes, 64-node blocks. FAILED replay:
//     read-before-write of poisoned ws (call-1 zeros vs 0xAA later).
// R5: blanket hipMemsetAsync(0) of the whole used ws span every call
//     (reproduces validated call-1 conditions deterministically); cursor-based
//     CSR fill (R3-proven) fused over 4 segments; no buffer aliasing.

#define TPB 256
#define SCAN_T 1024
#define IDX_CAP 2048

typedef _Float16 h8 __attribute__((ext_vector_type(8)));
typedef float f8 __attribute__((ext_vector_type(8)));

// ---------- CSR build (3 graphs, 4 edge segments, fused) ----------

struct Seg { const int* dst; int n; int* cnt; };
struct FSeg { const int* src; const int* dst; int n; const int* offs; int* cur; };

__global__ void count4(Seg s0, Seg s1, Seg s2, Seg s3) {
    int i = blockIdx.x * blockDim.x + threadIdx.x;
    Seg s; int e;
    if (i < s0.n) { s = s0; e = i; }
    else if (i < s0.n + s1.n) { s = s1; e = i - s0.n; }
    else if (i < s0.n + s1.n + s2.n) { s = s2; e = i - s0.n - s1.n; }
    else if (i < s0.n + s1.n + s2.n + s3.n) { s = s3; e = i - s0.n - s1.n - s2.n; }
    else return;
    atomicAdd(&s.cnt[s.dst[e]], 1);
}

__global__ void fill4(FSeg s0, FSeg s1, FSeg s2, FSeg s3, int* __restrict__ csr) {
    int i = blockIdx.x * blockDim.x + threadIdx.x;
    FSeg s; int e;
    if (i < s0.n) { s = s0; e = i; }
    else if (i < s0.n + s1.n) { s = s1; e = i - s0.n; }
    else if (i < s0.n + s1.n + s2.n) { s = s2; e = i - s0.n - s1.n; }
    else if (i < s0.n + s1.n + s2.n + s3.n) { s = s3; e = i - s0.n - s1.n - s2.n; }
    else return;
    int d = s.dst[e];
    int pos = s.offs[d] + atomicAdd(&s.cur[d], 1);
    csr[pos] = s.src[e];
}

__global__ void dinv_from_cnt(const int* __restrict__ cnt, float* __restrict__ dinv, int n) {
    int i = blockIdx.x * blockDim.x + threadIdx.x;
    if (i < n) dinv[i] = rsqrtf(1.0f + (float)cnt[i]);
}

__global__ void scan_block(const int* __restrict__ in, int n, int* __restrict__ out,
                           int* __restrict__ bsums) {
    __shared__ int sh[SCAN_T];
    int tx = threadIdx.x;
    int g = blockIdx.x * SCAN_T + tx;
    int v = (g < n) ? in[g] : 0;
    sh[tx] = v;
    __syncthreads();
    for (int off = 1; off < SCAN_T; off <<= 1) {
        int t = (tx >= off) ? sh[tx - off] : 0;
        __syncthreads();
        sh[tx] += t;
        __syncthreads();
    }
    if (g < n) out[g] = sh[tx] - v; // exclusive
    if (tx == SCAN_T - 1) bsums[blockIdx.x] = sh[tx];
}

__global__ void scan_sums(int* __restrict__ bsums, int nb) {
    __shared__ int sh[SCAN_T];
    int tx = threadIdx.x;
    int v = (tx < nb) ? bsums[tx] : 0;
    sh[tx] = v;
    __syncthreads();
    for (int off = 1; off < SCAN_T; off <<= 1) {
        int t = (tx >= off) ? sh[tx - off] : 0;
        __syncthreads();
        sh[tx] += t;
        __syncthreads();
    }
    if (tx < nb) bsums[tx] = sh[tx] - v;
}

__global__ void scan_add(int* __restrict__ offs, const int* __restrict__ bsums, int n, int total) {
    int g = blockIdx.x * blockDim.x + threadIdx.x;
    if (g < n) offs[g] += bsums[g >> 10]; // SCAN_T=1024 partitioning
    if (g == 0) offs[n] = total;
}

// ---------- seed matmuls: hs16 = fp16(dinv * (x @ W)) ----------

__global__ void mm32_kernel(const float* __restrict__ x, const float* __restrict__ W,
                            const float* __restrict__ dinv, _Float16* __restrict__ hs, int N) {
    __shared__ float Ws[32][32];
    __shared__ float xs[8][32];
    int tid = threadIdx.x;
    for (int i = tid; i < 32 * 32; i += TPB) Ws[i >> 5][i & 31] = W[i];
    int base = blockIdx.x * 8;
    {
        int idx = base * 32 + tid;
        xs[tid >> 5][tid & 31] = (idx < N * 32) ? x[idx] : 0.0f;
    }
    __syncthreads();
    int row = tid >> 5, c = tid & 31;
    int gr = base + row;
    float acc = 0.0f;
#pragma unroll
    for (int k = 0; k < 32; ++k) acc += xs[row][k] * Ws[k][c];
    if (gr < N) hs[gr * 32 + c] = (_Float16)(acc * dinv[gr]);
}

__global__ void mm128_kernel(const float* __restrict__ x, const float* __restrict__ W,
                             const float* __restrict__ dinv, _Float16* __restrict__ hs, int N) {
    __shared__ float Ws[128][32]; // 16 KB
    __shared__ float xs[8][128];  // 4 KB
    int tid = threadIdx.x;
    for (int i = tid; i < 128 * 32; i += TPB) Ws[i >> 5][i & 31] = W[i];
    int base = blockIdx.x * 8;
    for (int i = tid; i < 8 * 128; i += TPB) {
        int idx = base * 128 + i;
        xs[i >> 7][i & 127] = (idx < N * 128) ? x[idx] : 0.0f;
    }
    __syncthreads();
    int row = tid >> 5, c = tid & 31;
    int gr = base + row;
    float acc = 0.0f;
#pragma unroll
    for (int k = 0; k < 128; ++k) acc += xs[row][k] * Ws[k][c];
    if (gr < N) hs[gr * 32 + c] = (_Float16)(acc * dinv[gr]);
}

// ---------- fused CSR aggregate + RK4 stage + next matmul ----------

struct Job {
    const int* offs; const int* csr;
    const _Float16* hs_in; _Float16* hs_out;
    const float* dinv; const float* dinv_next;
    const float* bias; const float* wt;
    float* ksum; float* x;
    const float* W;
};

// 4 lanes/node (8 channels each), 64 nodes/block. blocks [0,nbp) -> jp else jn.
// pre = dinv[d]*(sum hs_in[src] + hs_in[d]); kv = relu(pre+b)[*sigmoid(t*wt)]
// stage 0: x=kv; x2=kv;           xrow=kv
// stage 1: ksum=kv;               xrow=x+0.05*kv
// stage 2: ksum+=2kv;             xrow=x+0.05*kv
// stage 3: ksum+=2kv;             xrow=x+0.1*kv
// stage 4: x+=(0.1/6)*(ksum+kv);  xrow=x
// if do_mm: hs_out[node] = fp16(dinv_next[node] * (xrow @ W))
__global__ __launch_bounds__(TPB) void agg_stage(Job jp, Job jn, int nbp, float t,
                                                 int stage, int do_mm, float* __restrict__ x2,
                                                 int N) {
    __shared__ float Ws[32][32];  // 4 KB
    __shared__ float xts[64][36]; // 9 KB (stride 36)
    __shared__ int sidx[IDX_CAP]; // 8 KB
    __shared__ int soffs[65];

    bool isP = blockIdx.x < nbp;
    const Job& J = isP ? jp : jn;
    int bid = isP ? blockIdx.x : (blockIdx.x - nbp);
    int nbase = bid * 64;
    int tid = threadIdx.x;
    int lnode = tid >> 2, q = tid & 3;
    int node = nbase + lnode;
    bool valid = node < N;

    if (do_mm) {
        for (int i = tid; i < 32 * 32; i += TPB) Ws[i >> 5][i & 31] = J.W[i];
    }
    int nend = nbase + 64; if (nend > N) nend = N;
    int e_lo = J.offs[nbase];
    int e_hi = J.offs[nend];
    int cnt = e_hi - e_lo;
    int staged = cnt < IDX_CAP ? cnt : IDX_CAP;
    for (int i = tid; i < staged; i += TPB) sidx[i] = J.csr[e_lo + i];
    if (tid < 65) {
        int ix = nbase + tid; if (ix > N) ix = N;
        soffs[tid] = J.offs[ix];
    }
    __syncthreads();

    f8 xrow;
#pragma unroll
    for (int j = 0; j < 8; ++j) xrow[j] = 0.f;

    if (valid) {
        const h8* hsv = (const h8*)J.hs_in;
        int r0 = soffs[lnode] - e_lo;
        int r1 = soffs[lnode + 1] - e_lo;
        f8 acc = __builtin_convertvector(hsv[node * 4 + q], f8); // self-loop
        int i = r0;
        int lim = r1 < staged ? r1 : staged;
        for (; i + 4 <= lim; i += 4) {
            h8 v0 = hsv[sidx[i] * 4 + q];
            h8 v1 = hsv[sidx[i + 1] * 4 + q];
            h8 v2 = hsv[sidx[i + 2] * 4 + q];
            h8 v3 = hsv[sidx[i + 3] * 4 + q];
            acc += (__builtin_convertvector(v0, f8) + __builtin_convertvector(v1, f8))
                 + (__builtin_convertvector(v2, f8) + __builtin_convertvector(v3, f8));
        }
        for (; i < lim; ++i)
            acc += __builtin_convertvector(hsv[sidx[i] * 4 + q], f8);
        for (; i < r1; ++i) // LDS overflow tail (init graph only)
            acc += __builtin_convertvector(hsv[J.csr[e_lo + i] * 4 + q], f8);

        float dv = J.dinv[node];
        f8 bb = ((const f8*)J.bias)[q];
        f8 kv;
#pragma unroll
        for (int j = 0; j < 8; ++j) kv[j] = fmaxf(acc[j] * dv + bb[j], 0.f);
        if (J.wt) {
            f8 w = ((const f8*)J.wt)[q];
#pragma unroll
            for (int j = 0; j < 8; ++j) kv[j] *= 1.f / (1.f + expf(-t * w[j]));
        }
        int idx = node * 4 + q;
        f8* x8 = (f8*)J.x;
        f8* ks8 = (f8*)J.ksum;
        if (stage == 0) {
            x8[idx] = kv;
            ((f8*)x2)[idx] = kv;
            xrow = kv;
        } else if (stage == 4) {
            f8 ks = ks8[idx];
            f8 xv = x8[idx];
            const float cc = 0.1f / 6.0f;
#pragma unroll
            for (int j = 0; j < 8; ++j) xv[j] += cc * (ks[j] + kv[j]);
            x8[idx] = xv;
            xrow = xv;
        } else {
            float a = (stage == 3) ? 0.1f : 0.05f;
            f8 xv = x8[idx];
#pragma unroll
            for (int j = 0; j < 8; ++j) xrow[j] = xv[j] + a * kv[j];
            if (stage == 1) {
                ks8[idx] = kv;
            } else {
                f8 ks = ks8[idx];
#pragma unroll
                for (int j = 0; j < 8; ++j) ks[j] += 2.f * kv[j];
                ks8[idx] = ks;
            }
        }
    }

    if (do_mm) {
        if (valid) {
#pragma unroll
            for (int j = 0; j < 8; ++j) xts[lnode][q * 8 + j] = xrow[j];
        }
        __syncthreads();
        if (valid) {
            f8 accm;
#pragma unroll
            for (int j = 0; j < 8; ++j) accm[j] = 0.f;
#pragma unroll
            for (int k = 0; k < 32; ++k) {
                float xv = xts[lnode][k];
                f8 w = *(const f8*)&Ws[k][q * 8];
                accm += xv * w;
            }
            accm *= J.dinv_next[node];
            ((h8*)J.hs_out)[node * 4 + q] = __builtin_convertvector(accm, h8);
        }
    }
}

// ---------- combine + layernorm ----------

__global__ void combine_kernel(const float* __restrict__ zp, const float* __restrict__ zn,
                               const float* __restrict__ Wc, const float* __restrict__ bc,
                               const float* __restrict__ g, const float* __restrict__ be,
                               float* __restrict__ out, int N) {
    __shared__ float Ws[64][32];
    __shared__ float zs[8][64];
    int tid = threadIdx.x;
    for (int i = tid; i < 64 * 32; i += TPB) Ws[i >> 5][i & 31] = Wc[i];
    int base = blockIdx.x * 8;
    {
        int r = tid >> 5, c = tid & 31;
        int gr = base + r;
        zs[r][c] = (gr < N) ? zp[gr * 32 + c] : 0.0f;
        zs[r][32 + c] = (gr < N) ? zn[gr * 32 + c] : 0.0f;
    }
    __syncthreads();
    int row = tid >> 5, c = tid & 31;
    int gr = base + row;
    float acc = bc[c];
#pragma unroll
    for (int k = 0; k < 64; ++k) acc += zs[row][k] * Ws[k][c];
    float s = acc, sq = acc * acc;
#pragma unroll
    for (int off = 16; off; off >>= 1) {
        s += __shfl_xor(s, off, 32);
        sq += __shfl_xor(sq, off, 32);
    }
    float mu = s * (1.0f / 32.0f);
    float var = sq * (1.0f / 32.0f) - mu * mu;
    float y = (acc - mu) * rsqrtf(var + 1e-5f) * g[c] + be[c];
    if (gr < N) out[gr * 32 + c] = y;
}

// ---------- host orchestration ----------

extern "C" void kernel_launch(void* const* d_in, const int* in_sizes, int n_in,
                              void* d_out, int out_size, void* d_ws, size_t ws_size,
                              hipStream_t stream) {
    const float* H_t = (const float*)d_in[0];
    const int* Apos = (const int*)d_in[1];
    const int* Aneg = (const int*)d_in[2];
    const int* dApos = (const int*)d_in[3];
    const int* dAneg = (const int*)d_in[4];
    const float* W_init = (const float*)d_in[5];
    const float* b_init = (const float*)d_in[6];
    const float* W_pos = (const float*)d_in[7];
    const float* b_pos = (const float*)d_in[8];
    const float* wt_pos = (const float*)d_in[9];
    const float* W_neg = (const float*)d_in[10];
    const float* b_neg = (const float*)d_in[11];
    const float* wt_neg = (const float*)d_in[12];
    const float* W_comb = (const float*)d_in[13];
    const float* b_comb = (const float*)d_in[14];
    const float* ln_g = (const float*)d_in[15];
    const float* ln_b = (const float*)d_in[16];

    const int N = in_sizes[0] / 128;
    const int E1 = in_sizes[1] / 2;
    const int E2 = in_sizes[2] / 2;
    const int DE1 = in_sizes[3] / 2;
    const int DE2 = in_sizes[4] / 2;
    const int Etot = E1 + E2 + DE1 + DE2;

    const int* Apos_src = Apos, * Apos_dst = Apos + E1;
    const int* Aneg_src = Aneg, * Aneg_dst = Aneg + E2;
    const int* dApos_src = dApos, * dApos_dst = dApos + DE1;
    const int* dAneg_src = dAneg, * dAneg_dst = dAneg + DE2;

    const size_t n32 = (size_t)N * 32;
    const size_t szf = n32 * 4;   // fp32 state buffer
    const size_t szh = n32 * 2;   // fp16 hs buffer
    auto al = [](size_t b) { return (b + 255) & ~(size_t)255; };

    // footprint if merged (4 fp32 + 4 fp16 + small)
    size_t small_bytes = 3 * al((size_t)(3 * N) * 4)      /* dinv3, cnt3, cur3 */
                       + al((3 * (size_t)N + 1) * 4)      /* offs3 */
                       + al((size_t)Etot * 4)             /* csr3 */
                       + al(SCAN_T * 4);                  /* bsums */
    size_t need_merged = 4 * al(szf) + 4 * al(szh) + small_bytes;
    bool merged = ws_size >= need_merged + 4096;

    char* p = (char*)d_ws;
    auto alloc = [&](size_t bytes) -> void* {
        void* r = (void*)p;
        p += al(bytes);
        return r;
    };
    float* x_pos = (float*)alloc(szf);
    float* x_neg = (float*)alloc(szf);
    float* ksum_p = (float*)alloc(szf);
    float* ksum_n = merged ? (float*)alloc(szf) : ksum_p;
    _Float16* hs_pa = (_Float16*)alloc(szh);
    _Float16* hs_pb = (_Float16*)alloc(szh);
    _Float16* hs_na = merged ? (_Float16*)alloc(szh) : hs_pa;
    _Float16* hs_nb = merged ? (_Float16*)alloc(szh) : hs_pb;
    float* dinv3 = (float*)alloc((size_t)(3 * N) * 4);
    int* cnt3 = (int*)alloc((size_t)(3 * N) * 4);
    int* cur3 = (int*)alloc((size_t)(3 * N) * 4);
    int* offs3 = (int*)alloc((3 * (size_t)N + 1) * 4);
    int* csr3 = (int*)alloc((size_t)Etot * 4);
    int* bsums = (int*)alloc(SCAN_T * 4);

    size_t used = (size_t)(p - (char*)d_ws);
    if (used > ws_size) used = ws_size; // can't do better; layout assumed to fit

    // R5: blanket zero of every ws byte we use — reproduces validated call-1
    // initial conditions on every call/replay (harness poisons ws with 0xAA).
    hipMemsetAsync(d_ws, 0, used, stream);

    float* dinv_all = dinv3, * dinv_pos = dinv3 + N, * dinv_neg = dinv3 + 2 * N;
    int* cnt_all = cnt3, * cnt_pos = cnt3 + N, * cnt_neg = cnt3 + 2 * N;
    int* cur_all = cur3, * cur_pos = cur3 + N, * cur_neg = cur3 + 2 * N;
    const int* offs_all = offs3, * offs_pos = offs3 + N, * offs_neg = offs3 + 2 * N;

    dim3 blk(TPB);
    auto gblk = [](int n) { return dim3((n + TPB - 1) / TPB); };
    dim3 grid_rows((N + 7) / 8);
    const int nb64 = (N + 63) / 64;
    const int n3 = 3 * N;
    const int nbs = (n3 + SCAN_T - 1) / SCAN_T;

    // ---- fused CSR build for all 3 graphs (cnt3/cur3 zeroed by blanket memset) ----
    {
        Seg s0 = { Apos_dst, E1, cnt_all };
        Seg s1 = { Aneg_dst, E2, cnt_all };
        Seg s2 = { dApos_dst, DE1, cnt_pos };
        Seg s3 = { dAneg_dst, DE2, cnt_neg };
        count4<<<gblk(Etot), blk, 0, stream>>>(s0, s1, s2, s3);
    }
    dinv_from_cnt<<<gblk(n3), blk, 0, stream>>>(cnt3, dinv3, n3);
    scan_block<<<nbs, SCAN_T, 0, stream>>>(cnt3, n3, offs3, bsums);
    scan_sums<<<1, SCAN_T, 0, stream>>>(bsums, nbs);
    scan_add<<<gblk(n3), blk, 0, stream>>>(offs3, bsums, n3, Etot);
    {
        FSeg f0 = { Apos_src, Apos_dst, E1, offs_all, cur_all };
        FSeg f1 = { Aneg_src, Aneg_dst, E2, offs_all, cur_all };
        FSeg f2 = { dApos_src, dApos_dst, DE1, offs_pos, cur_pos };
        FSeg f3 = { dAneg_src, dAneg_dst, DE2, offs_neg, cur_neg };
        fill4<<<gblk(Etot), blk, 0, stream>>>(f0, f1, f2, f3, csr3);
    }

    // ---- job descriptors ----
    auto mkjob = [&](const int* offs, const _Float16* hs_in, _Float16* hs_out,
                     const float* dinv, const float* dinv_next, const float* bias,
                     const float* wt, float* ksum, float* x, const float* W) {
        Job j; j.offs = offs; j.csr = csr3; j.hs_in = hs_in; j.hs_out = hs_out;
        j.dinv = dinv; j.dinv_next = dinv_next; j.bias = bias; j.wt = wt;
        j.ksum = ksum; j.x = x; j.W = W; return j;
    };

    // ---- init GCN: H0 = relu(gcn(H_t)) -> x_pos, x_neg; epilogue seeds pos hs ----
    mm128_kernel<<<grid_rows, blk, 0, stream>>>(H_t, W_init, dinv_all, hs_pa, N);
    {
        Job j0 = mkjob(offs_all, hs_pa, hs_pb, dinv_all, dinv_pos, b_init,
                       nullptr, nullptr, x_pos, W_pos);
        agg_stage<<<nb64, blk, 0, stream>>>(j0, j0, nb64, 0.0f, 0, 1, x_neg, N);
    }

    if (merged) {
        // seed hs for neg ODE
        mm32_kernel<<<grid_rows, blk, 0, stream>>>(x_neg, W_neg, dinv_neg, hs_nb, N);
        for (int s = 0; s < 10; ++s) {
            float t0 = 0.1f * (float)s;
            int last_mm = (s == 9) ? 0 : 1;
            Job p1 = mkjob(offs_pos, hs_pb, hs_pa, dinv_pos, dinv_pos, b_pos, wt_pos, ksum_p, x_pos, W_pos);
            Job n1 = mkjob(offs_neg, hs_nb, hs_na, dinv_neg, dinv_neg, b_neg, wt_neg, ksum_n, x_neg, W_neg);
            agg_stage<<<2 * nb64, blk, 0, stream>>>(p1, n1, nb64, t0, 1, 1, nullptr, N);
            Job p2 = p1; p2.hs_in = hs_pa; p2.hs_out = hs_pb;
            Job n2 = n1; n2.hs_in = hs_na; n2.hs_out = hs_nb;
            agg_stage<<<2 * nb64, blk, 0, stream>>>(p2, n2, nb64, t0 + 0.05f, 2, 1, nullptr, N);
            agg_stage<<<2 * nb64, blk, 0, stream>>>(p1, n1, nb64, t0 + 0.05f, 3, 1, nullptr, N);
            agg_stage<<<2 * nb64, blk, 0, stream>>>(p2, n2, nb64, t0 + 0.1f, 4, last_mm, nullptr, N);
        }
    } else {
        for (int ode = 0; ode < 2; ++ode) {
            float* x = ode ? x_neg : x_pos;
            const float* W = ode ? W_neg : W_pos;
            const float* b = ode ? b_neg : b_pos;
            const float* wt = ode ? wt_neg : wt_pos;
            const float* dinv = ode ? dinv_neg : dinv_pos;
            const int* offs = ode ? offs_neg : offs_pos;
            if (ode == 1) {
                // seed: hs_pb was clobbered by pos ODE
                mm32_kernel<<<grid_rows, blk, 0, stream>>>(x, W, dinv, hs_pb, N);
            }
            for (int s = 0; s < 10; ++s) {
                float t0 = 0.1f * (float)s;
                int last_mm = (s == 9) ? 0 : 1;
                Job j1 = mkjob(offs, hs_pb, hs_pa, dinv, dinv, b, wt, ksum_p, x, W);
                Job j2 = j1; j2.hs_in = hs_pa; j2.hs_out = hs_pb;
                agg_stage<<<nb64, blk, 0, stream>>>(j1, j1, nb64, t0, 1, 1, nullptr, N);
                agg_stage<<<nb64, blk, 0, stream>>>(j2, j2, nb64, t0 + 0.05f, 2, 1, nullptr, N);
                agg_stage<<<nb64, blk, 0, stream>>>(j1, j1, nb64, t0 + 0.05f, 3, 1, nullptr, N);
                agg_stage<<<nb64, blk, 0, stream>>>(j2, j2, nb64, t0 + 0.1f, 4, last_mm, nullptr, N);
            }
        }
    }

    // ---- combine + layernorm ----
    combine_kernel<<<grid_rows, blk, 0, stream>>>(x_pos, x_neg, W_comb, b_comb, ln_g, ln_b,
                                                  (float*)d_out, N);
}